// Round 1
// 1229.855 us; speedup vs baseline: 1.1035x; 1.1035x over previous
//
#include <hip/hip_runtime.h>
#include <stdint.h>

typedef unsigned short u16;

#define B_   2
#define S_   2048
#define H_   4096
#define NH   32
#define NKV  8
#define HD   128
#define KVD  (NKV * HD)   // 1024
#define BS   (B_ * S_)    // 4096

typedef __bf16 bf16x8 __attribute__((ext_vector_type(8)));
typedef u16    u16x8  __attribute__((ext_vector_type(8)));
typedef u16    u16x4  __attribute__((ext_vector_type(4)));
typedef float  f32x4  __attribute__((ext_vector_type(4)));

__device__ __forceinline__ bf16x8 as_bf16x8(u16x8 v) { return __builtin_bit_cast(bf16x8, v); }

__device__ __forceinline__ float bf2f(u16 u) {
  union { uint32_t u; float f; } v; v.u = ((uint32_t)u) << 16; return v.f;
}
__device__ __forceinline__ u16 f2bf(float f) {
  union { float f; uint32_t u; } v; v.f = f;
  uint32_t r = v.u + 0x7FFFu + ((v.u >> 16) & 1u);
  return (u16)(r >> 16);
}

// async global->LDS, 16B per lane; LDS dest must be wave-uniform-base + lane*16
__device__ __forceinline__ void gload_lds16(const void* g, void* l) {
  __builtin_amdgcn_global_load_lds((const __attribute__((address_space(1))) void*)g,
                                   (__attribute__((address_space(3))) void*)l, 16, 0, 0);
}

// ---------------------------------------------------------------------------
// fp32 -> bf16 elementwise (vectorized, 8 elems/thread)
// ---------------------------------------------------------------------------
__global__ __launch_bounds__(256) void conv_bf16(const float* __restrict__ in,
                                                 u16* __restrict__ out) {
  size_t i = ((size_t)blockIdx.x * 256 + threadIdx.x) * 8;
  float4 a = *(const float4*)(in + i);
  float4 b = *(const float4*)(in + i + 4);
  u16x8 h;
  h[0] = f2bf(a.x); h[1] = f2bf(a.y); h[2] = f2bf(a.z); h[3] = f2bf(a.w);
  h[4] = f2bf(b.x); h[5] = f2bf(b.y); h[6] = f2bf(b.z); h[7] = f2bf(b.w);
  *(u16x8*)(out + i) = h;
}

// ---------------------------------------------------------------------------
// Convert + transpose: fp32 in[R][C] -> bf16 out[C][R]; 64x64 tiles.
// ---------------------------------------------------------------------------
__global__ __launch_bounds__(256) void conv_transpose_w(const float* __restrict__ in,
                                                        u16* __restrict__ out,
                                                        int ldi, int ldo) {
  __shared__ u16 tile[64][72];
  int r0 = blockIdx.x * 64, c0 = blockIdx.y * 64;
  int t = threadIdx.x;
  {
    int row = t >> 4, col = (t & 15) * 4;
#pragma unroll
    for (int rep = 0; rep < 4; ++rep) {
      int r = row + rep * 16;
      float4 v = *(const float4*)(in + (size_t)(r0 + r) * ldi + c0 + col);
      u16x4 h;
      h[0] = f2bf(v.x); h[1] = f2bf(v.y); h[2] = f2bf(v.z); h[3] = f2bf(v.w);
      *(u16x4*)&tile[r][col] = h;
    }
  }
  __syncthreads();
  {
    int row = t >> 2, c8 = (t & 3) * 8;
#pragma unroll
    for (int it = 0; it < 2; ++it) {
      int rr = c8 + it * 32;
      u16x8 v;
#pragma unroll
      for (int j = 0; j < 8; ++j) v[j] = tile[rr + j][row];
      *(u16x8*)(out + (size_t)(c0 + row) * ldo + r0 + rr) = v;
    }
  }
}

// ---------------------------------------------------------------------------
// V transpose (bf16): V[b*S_+s][kvh*HD+d] -> Vt[((b*NKV+kvh)*HD + d)*S_ + s]
// ---------------------------------------------------------------------------
__global__ __launch_bounds__(256) void transpose_v(const u16* __restrict__ V,
                                                   u16* __restrict__ Vt) {
  __shared__ u16 tile[64][72];
  int g = blockIdx.z;
  const u16* in = V + (size_t)(g >> 3) * ((size_t)S_ * KVD) + (size_t)(g & 7) * HD;
  u16* out = Vt + (size_t)g * ((size_t)HD * S_);
  int r0 = blockIdx.x * 64, c0 = blockIdx.y * 64;
  int t = threadIdx.x;
  int row = t >> 2, c8 = (t & 3) * 8;
#pragma unroll
  for (int it = 0; it < 2; ++it) {
    int col = c8 + it * 32;
    *(u16x8*)&tile[row][col] = *(const u16x8*)(in + (size_t)(r0 + row) * KVD + c0 + col);
  }
  __syncthreads();
#pragma unroll
  for (int it = 0; it < 2; ++it) {
    int rr = c8 + it * 32;
    u16x8 v;
#pragma unroll
    for (int j = 0; j < 8; ++j) v[j] = tile[rr + j][row];
    *(u16x8*)(out + (size_t)(c0 + row) * S_ + r0 + rr) = v;
  }
}

// ---------------------------------------------------------------------------
// C[M][N] = A[M][K] @ Bt[N][K]^T.  A bf16, C bf16 or fp32.
// m97 structure: 128x128 tile, BK=32, global_load_lds dwordx4 staging,
// 4 waves of 64x64, 16x16x32 bf16 MFMA.
// ---------------------------------------------------------------------------
template <bool C_F32>
__global__ __launch_bounds__(256) void gemm_bt_lds(const u16* __restrict__ A,
                                                   const u16* __restrict__ Bt,
                                                   void* __restrict__ Cp,
                                                   int M, int N, int K) {
  __shared__ __align__(16) u16 lsA[128][32];
  __shared__ __align__(16) u16 lsB[128][32];
  int t = threadIdx.x;
  int lane = t & 63;
  int w = t >> 6;
  int wm = (w >> 1) * 64, wn = (w & 1) * 64;
  int bm = blockIdx.x * 128, bn = blockIdx.y * 128;
  int fr = lane & 15, kq = lane >> 4;
  f32x4 acc[4][4] = {};

  // staging chunk: chunk = t (+256), row = chunk>>2, col16 = chunk&3.
  // LDS byte offset = chunk*16 => linear in lane (global_load_lds constraint).
  int sr = t >> 2, sc = (t & 3) * 8;
  const u16* Ar0 = A + (size_t)(bm + sr) * K + sc;
  const u16* Ar1 = A + (size_t)(bm + sr + 64) * K + sc;
  const u16* Br0 = Bt + (size_t)(bn + sr) * K + sc;
  const u16* Br1 = Bt + (size_t)(bn + sr + 64) * K + sc;
  u16* lA0 = &lsA[sr][sc];
  u16* lA1 = &lsA[sr + 64][sc];
  u16* lB0 = &lsB[sr][sc];
  u16* lB1 = &lsB[sr + 64][sc];

  for (int k0 = 0; k0 < K; k0 += 32) {
    gload_lds16(Ar0 + k0, lA0);
    gload_lds16(Ar1 + k0, lA1);
    gload_lds16(Br0 + k0, lB0);
    gload_lds16(Br1 + k0, lB1);
    __syncthreads();  // drains vmcnt(0): LDS tiles complete
    bf16x8 af[4], bfr[4];
#pragma unroll
    for (int i = 0; i < 4; ++i) af[i] = as_bf16x8(*(const u16x8*)&lsA[wm + i * 16 + fr][kq * 8]);
#pragma unroll
    for (int j = 0; j < 4; ++j) bfr[j] = as_bf16x8(*(const u16x8*)&lsB[wn + j * 16 + fr][kq * 8]);
#pragma unroll
    for (int i = 0; i < 4; ++i)
#pragma unroll
      for (int j = 0; j < 4; ++j)
        acc[i][j] = __builtin_amdgcn_mfma_f32_16x16x32_bf16(af[i], bfr[j], acc[i][j], 0, 0, 0);
    __syncthreads();  // protect LDS from next-iter staging
  }
#pragma unroll
  for (int i = 0; i < 4; ++i)
#pragma unroll
    for (int j = 0; j < 4; ++j)
#pragma unroll
      for (int r = 0; r < 4; ++r) {
        int row = bm + wm + i * 16 + kq * 4 + r;
        int col = bn + wn + j * 16 + fr;
        if (C_F32) ((float*)Cp)[(size_t)row * N + col] = acc[i][j][r];
        else       ((u16*)Cp)[(size_t)row * N + col] = f2bf(acc[i][j][r]);
      }
}

// ---------------------------------------------------------------------------
// RoPE in-place on bf16 Q [BS][H_] and K [BS][KVD].
// ---------------------------------------------------------------------------
__global__ __launch_bounds__(256) void rope_kernel(u16* __restrict__ Q,
                                                   u16* __restrict__ Kp) {
  int idx = blockIdx.x * 256 + threadIdx.x;  // BS * 40 * 64 total
  int j = idx & 63;
  int rem = idx >> 6;
  int hh = rem % 40;
  int tok = rem / 40;
  float p = (float)(tok % S_);
  float freq = __expf((float)j * (-9.210340371976184f / 64.0f));  // 10000^(-j/64)
  float sn, cs;
  __sincosf(p * freq, &sn, &cs);
  u16* base = (hh < NH) ? (Q + (size_t)tok * H_ + (size_t)hh * HD)
                        : (Kp + (size_t)tok * KVD + (size_t)(hh - NH) * HD);
  float x1 = bf2f(base[j]), x2 = bf2f(base[j + 64]);
  base[j]      = f2bf(x1 * cs - x2 * sn);
  base[j + 64] = f2bf(x2 * cs + x1 * sn);
}

// ---------------------------------------------------------------------------
// Flash attention, causal, GQA(4).  (unchanged this round — control)
// ---------------------------------------------------------------------------
__global__ __launch_bounds__(256) void flash_attn(const u16* __restrict__ Q,
                                                  const u16* __restrict__ Kp,
                                                  const u16* __restrict__ Vt,
                                                  u16* __restrict__ O) {
  __shared__ __align__(16) u16 Ks[64 * 128];   // [kv 64][d 128], swizzled
  __shared__ __align__(16) u16 Vs[128 * 64];   // [d 128][kv 64], swizzled
  __shared__ u16 Plds[4][16][72];              // per-wave P tile, +8 pad
  int qt = blockIdx.x, kvh = blockIdx.y, b = blockIdx.z;
  int t = threadIdx.x, lane = t & 63, w = t >> 6;
  int h = kvh * 4 + w;                         // this wave's head
  int fr = lane & 15, kq = lane >> 4;
  int q0 = qt * 16;

  const u16* qbase = Q + (size_t)(b * S_ + q0 + fr) * H_ + (size_t)h * HD;
  bf16x8 qf[4];
#pragma unroll
  for (int kk = 0; kk < 4; ++kk) qf[kk] = as_bf16x8(*(const u16x8*)(qbase + kk * 32 + kq * 8));

  f32x4 o[8] = {};
  float mrow[4] = {-1e30f, -1e30f, -1e30f, -1e30f};
  float lrow[4] = {0.f, 0.f, 0.f, 0.f};

  const u16* kbase = Kp + (size_t)(b * S_) * KVD + (size_t)kvh * HD;
  const u16* vbase = Vt + (size_t)(b * NKV + kvh) * ((size_t)HD * S_);
  const float scale = 0.08838834764831845f;  // 1/sqrt(128)

  int niter = (q0 + 15) / 64 + 1;
  for (int kt = 0; kt < niter; ++kt) {
    int k0 = kt * 64;
    if (kt) __syncthreads();
    // ---- stage K tile: 64 rows x 256B, 16B chunks, chunk' = c ^ (row&15)
#pragma unroll
    for (int ps = 0; ps < 4; ++ps) {
      int idx = ps * 256 + t;
      int row = idx >> 4, c = idx & 15;
      *(u16x8*)&Ks[row * 128 + ((c ^ row) & 15) * 8] =
          *(const u16x8*)(kbase + (size_t)(k0 + row) * KVD + c * 8);
    }
    // ---- stage V tile: 128 rows x 128B, 8B subchunks, sub' = s ^ (row&15)
#pragma unroll
    for (int ps = 0; ps < 4; ++ps) {
      int idx = ps * 256 + t;
      int row = idx >> 3, c = idx & 7;
      u16x8 v = *(const u16x8*)(vbase + (size_t)row * S_ + k0 + c * 8);
      u16x4 lo, hi;
#pragma unroll
      for (int i = 0; i < 4; ++i) { lo[i] = v[i]; hi[i] = v[4 + i]; }
      *(u16x4*)&Vs[row * 64 + (((2 * c) ^ (row & 15)) * 4)] = lo;
      *(u16x4*)&Vs[row * 64 + (((2 * c + 1) ^ (row & 15)) * 4)] = hi;
    }
    __syncthreads();

    // ---- S = Q K^T from LDS
    f32x4 s[4] = {};
#pragma unroll
    for (int kk = 0; kk < 4; ++kk) {
#pragma unroll
      for (int j = 0; j < 4; ++j) {
        bf16x8 kf = as_bf16x8(*(const u16x8*)&Ks[(j * 16 + fr) * 128 + (((kk * 4 + kq) ^ fr) & 15) * 8]);
        s[j] = __builtin_amdgcn_mfma_f32_16x16x32_bf16(qf[kk], kf, s[j], 0, 0, 0);
      }
    }
    // ---- scale + causal mask + row max
    float mt[4] = {-1e30f, -1e30f, -1e30f, -1e30f};
#pragma unroll
    for (int j = 0; j < 4; ++j) {
      int kv = k0 + j * 16 + fr;
#pragma unroll
      for (int r = 0; r < 4; ++r) {
        int qr = q0 + kq * 4 + r;
        float sv = (kv <= qr) ? s[j][r] * scale : -1e30f;
        s[j][r] = sv;
        mt[r] = fmaxf(mt[r], sv);
      }
    }
#pragma unroll
    for (int off = 1; off < 16; off <<= 1)
#pragma unroll
      for (int r = 0; r < 4; ++r) mt[r] = fmaxf(mt[r], __shfl_xor(mt[r], off, 64));

    float alpha[4], lt[4];
#pragma unroll
    for (int r = 0; r < 4; ++r) {
      float mn = fmaxf(mrow[r], mt[r]);
      alpha[r] = __expf(mrow[r] - mn);
      mrow[r] = mn;
      lt[r] = 0.f;
    }
#pragma unroll
    for (int j = 0; j < 4; ++j)
#pragma unroll
      for (int r = 0; r < 4; ++r) {
        float p = __expf(s[j][r] - mrow[r]);
        s[j][r] = p;
        lt[r] += p;
      }
#pragma unroll
    for (int off = 1; off < 16; off <<= 1)
#pragma unroll
      for (int r = 0; r < 4; ++r) lt[r] += __shfl_xor(lt[r], off, 64);
#pragma unroll
    for (int r = 0; r < 4; ++r) lrow[r] = lrow[r] * alpha[r] + lt[r];
#pragma unroll
    for (int tt = 0; tt < 8; ++tt)
#pragma unroll
      for (int r = 0; r < 4; ++r) o[tt][r] *= alpha[r];

    // ---- P (C-layout) -> per-wave LDS -> A-layout frags
#pragma unroll
    for (int j = 0; j < 4; ++j)
#pragma unroll
      for (int r = 0; r < 4; ++r)
        Plds[w][kq * 4 + r][j * 16 + fr] = f2bf(s[j][r]);

#pragma unroll
    for (int st = 0; st < 2; ++st) {
      bf16x8 pf = as_bf16x8(*(const u16x8*)&Plds[w][fr][st * 32 + kq * 8]);
#pragma unroll
      for (int tt = 0; tt < 8; ++tt) {
        int rr = tt * 16 + fr;
        int s0 = ((st * 8 + kq * 2) ^ (fr & 15)) * 4;
        int s1 = ((st * 8 + kq * 2 + 1) ^ (fr & 15)) * 4;
        u16x4 lo = *(const u16x4*)&Vs[rr * 64 + s0];
        u16x4 hi = *(const u16x4*)&Vs[rr * 64 + s1];
        u16x8 vv;
#pragma unroll
        for (int i = 0; i < 4; ++i) { vv[i] = lo[i]; vv[4 + i] = hi[i]; }
        o[tt] = __builtin_amdgcn_mfma_f32_16x16x32_bf16(pf, as_bf16x8(vv), o[tt], 0, 0, 0);
      }
    }
  }

  float inv[4];
#pragma unroll
  for (int r = 0; r < 4; ++r) inv[r] = 1.0f / lrow[r];
  u16* obase = O + (size_t)(b * S_ + q0) * H_ + (size_t)h * HD;
#pragma unroll
  for (int tt = 0; tt < 8; ++tt)
#pragma unroll
    for (int r = 0; r < 4; ++r)
      obase[(size_t)(kq * 4 + r) * H_ + tt * 16 + fr] = f2bf(o[tt][r] * inv[r]);
}

// ---------------------------------------------------------------------------
extern "C" void kernel_launch(void* const* d_in, const int* in_sizes, int n_in,
                              void* d_out, int out_size, void* d_ws, size_t ws_size,
                              hipStream_t stream) {
  const float* X  = (const float*)d_in[0];
  const float* Wq = (const float*)d_in[2];
  const float* Wk = (const float*)d_in[3];
  const float* Wv = (const float*)d_in[4];
  const float* Wo = (const float*)d_in[5];
  float* out = (float*)d_out;

  // ws (80 MiB): K 8 | Vt 8 | {Xb -> Ob} 32 | Wt 32   (bf16)
  // Xb (bf16 X) time-shares the Ob slot: Xb dead after V projection,
  // Ob first written by flash_attn.
  char* ws = (char*)d_ws;
  u16* Kb = (u16*)ws;
  u16* Vt = (u16*)(ws + 8ull  * 1024 * 1024);
  u16* Xb = (u16*)(ws + 16ull * 1024 * 1024);
  u16* Ob = (u16*)(ws + 16ull * 1024 * 1024);
  u16* Wt = (u16*)(ws + 48ull * 1024 * 1024);
  // d_out is 64 MiB fp32; park bf16 Q (32 MiB) and pre-transpose V (8 MiB)
  // there — both dead before the final GEMM overwrites all of d_out.
  u16* Qb = (u16*)d_out;
  u16* Vb = (u16*)((char*)d_out + 32ull * 1024 * 1024);

  dim3 blk(256);

  // X -> bf16 (once; enables global_load_lds staging in all GEMMs)
  conv_bf16<<<dim3((size_t)BS * H_ / 8 / 256), blk, 0, stream>>>(X, Xb);

  // Q = X @ Wq
  conv_transpose_w<<<dim3(64, 64), blk, 0, stream>>>(Wq, Wt, H_, H_);
  gemm_bt_lds<false><<<dim3(32, 32), blk, 0, stream>>>(Xb, Wt, Qb, BS, H_, H_);
  // K = X @ Wk
  conv_transpose_w<<<dim3(64, 16), blk, 0, stream>>>(Wk, Wt, KVD, H_);
  gemm_bt_lds<false><<<dim3(32, 8), blk, 0, stream>>>(Xb, Wt, Kb, BS, KVD, H_);
  // V = X @ Wv
  conv_transpose_w<<<dim3(64, 16), blk, 0, stream>>>(Wv, Wt, KVD, H_);
  gemm_bt_lds<false><<<dim3(32, 8), blk, 0, stream>>>(Xb, Wt, Vb, BS, KVD, H_);
  // RoPE in-place on Q and K
  rope_kernel<<<dim3((BS * 40 * 64) / 256), blk, 0, stream>>>(Qb, Kb);
  // V -> Vt
  transpose_v<<<dim3(S_ / 64, HD / 64, B_ * NKV), blk, 0, stream>>>(Vb, Vt);
  // attention -> Ob
  flash_attn<<<dim3(S_ / 16, NKV, B_), blk, 0, stream>>>(Qb, Kb, Vt, Ob);
  // out = Ob @ Wo  (fp32 out, overwrites all of d_out)
  conv_transpose_w<<<dim3(64, 64), blk, 0, stream>>>(Wo, Wt, H_, H_);
  gemm_bt_lds<true><<<dim3(32, 32), blk, 0, stream>>>(Ob, Wt, out, BS, H_, H_);
}

// Round 2
// 1103.452 us; speedup vs baseline: 1.2299x; 1.1146x over previous
//
#include <hip/hip_runtime.h>
#include <stdint.h>

typedef unsigned short u16;

#define B_   2
#define S_   2048
#define H_   4096
#define NH   32
#define NKV  8
#define HD   128
#define KVD  (NKV * HD)   // 1024
#define BS   (B_ * S_)    // 4096

typedef __bf16 bf16x8 __attribute__((ext_vector_type(8)));
typedef u16    u16x8  __attribute__((ext_vector_type(8)));
typedef u16    u16x4  __attribute__((ext_vector_type(4)));
typedef float  f32x4  __attribute__((ext_vector_type(4)));

__device__ __forceinline__ bf16x8 as_bf16x8(u16x8 v) { return __builtin_bit_cast(bf16x8, v); }

__device__ __forceinline__ float bf2f(u16 u) {
  union { uint32_t u; float f; } v; v.u = ((uint32_t)u) << 16; return v.f;
}
__device__ __forceinline__ u16 f2bf(float f) {
  union { float f; uint32_t u; } v; v.f = f;
  uint32_t r = v.u + 0x7FFFu + ((v.u >> 16) & 1u);
  return (u16)(r >> 16);
}

// async global->LDS, 16B per lane; LDS dest must be wave-uniform-base + lane*16
__device__ __forceinline__ void gload_lds16(const void* g, void* l) {
  __builtin_amdgcn_global_load_lds((const __attribute__((address_space(1))) void*)g,
                                   (__attribute__((address_space(3))) void*)l, 16, 0, 0);
}

// ---------------------------------------------------------------------------
// fp32 -> bf16 elementwise (vectorized, 8 elems/thread)
// ---------------------------------------------------------------------------
__global__ __launch_bounds__(256) void conv_bf16(const float* __restrict__ in,
                                                 u16* __restrict__ out) {
  size_t i = ((size_t)blockIdx.x * 256 + threadIdx.x) * 8;
  float4 a = *(const float4*)(in + i);
  float4 b = *(const float4*)(in + i + 4);
  u16x8 h;
  h[0] = f2bf(a.x); h[1] = f2bf(a.y); h[2] = f2bf(a.z); h[3] = f2bf(a.w);
  h[4] = f2bf(b.x); h[5] = f2bf(b.y); h[6] = f2bf(b.z); h[7] = f2bf(b.w);
  *(u16x8*)(out + i) = h;
}

// ---------------------------------------------------------------------------
// Convert + transpose: fp32 in[R][C] -> bf16 out[C][R]; 64x64 tiles.
// ---------------------------------------------------------------------------
__global__ __launch_bounds__(256) void conv_transpose_w(const float* __restrict__ in,
                                                        u16* __restrict__ out,
                                                        int ldi, int ldo) {
  __shared__ u16 tile[64][72];
  int r0 = blockIdx.x * 64, c0 = blockIdx.y * 64;
  int t = threadIdx.x;
  {
    int row = t >> 4, col = (t & 15) * 4;
#pragma unroll
    for (int rep = 0; rep < 4; ++rep) {
      int r = row + rep * 16;
      float4 v = *(const float4*)(in + (size_t)(r0 + r) * ldi + c0 + col);
      u16x4 h;
      h[0] = f2bf(v.x); h[1] = f2bf(v.y); h[2] = f2bf(v.z); h[3] = f2bf(v.w);
      *(u16x4*)&tile[r][col] = h;
    }
  }
  __syncthreads();
  {
    int row = t >> 2, c8 = (t & 3) * 8;
#pragma unroll
    for (int it = 0; it < 2; ++it) {
      int rr = c8 + it * 32;
      u16x8 v;
#pragma unroll
      for (int j = 0; j < 8; ++j) v[j] = tile[rr + j][row];
      *(u16x8*)(out + (size_t)(c0 + row) * ldo + r0 + rr) = v;
    }
  }
}

// ---------------------------------------------------------------------------
// V transpose (bf16): V[b*S_+s][kvh*HD+d] -> Vt[((b*NKV+kvh)*HD + d)*S_ + s]
// ---------------------------------------------------------------------------
__global__ __launch_bounds__(256) void transpose_v(const u16* __restrict__ V,
                                                   u16* __restrict__ Vt) {
  __shared__ u16 tile[64][72];
  int g = blockIdx.z;
  const u16* in = V + (size_t)(g >> 3) * ((size_t)S_ * KVD) + (size_t)(g & 7) * HD;
  u16* out = Vt + (size_t)g * ((size_t)HD * S_);
  int r0 = blockIdx.x * 64, c0 = blockIdx.y * 64;
  int t = threadIdx.x;
  int row = t >> 2, c8 = (t & 3) * 8;
#pragma unroll
  for (int it = 0; it < 2; ++it) {
    int col = c8 + it * 32;
    *(u16x8*)&tile[row][col] = *(const u16x8*)(in + (size_t)(r0 + row) * KVD + c0 + col);
  }
  __syncthreads();
#pragma unroll
  for (int it = 0; it < 2; ++it) {
    int rr = c8 + it * 32;
    u16x8 v;
#pragma unroll
    for (int j = 0; j < 8; ++j) v[j] = tile[rr + j][row];
    *(u16x8*)(out + (size_t)(c0 + row) * S_ + r0 + rr) = v;
  }
}

// ---------------------------------------------------------------------------
// C[M][N] = A[M][K] @ Bt[N][K]^T.  A bf16, C bf16 or fp32.
// m97 structure: 128x128 tile, BK=32, global_load_lds dwordx4 staging,
// 4 waves of 64x64, 16x16x32 bf16 MFMA.
// ---------------------------------------------------------------------------
template <bool C_F32>
__global__ __launch_bounds__(256) void gemm_bt_lds(const u16* __restrict__ A,
                                                   const u16* __restrict__ Bt,
                                                   void* __restrict__ Cp,
                                                   int M, int N, int K) {
  __shared__ __align__(16) u16 lsA[128][32];
  __shared__ __align__(16) u16 lsB[128][32];
  int t = threadIdx.x;
  int lane = t & 63;
  int w = t >> 6;
  int wm = (w >> 1) * 64, wn = (w & 1) * 64;
  int bm = blockIdx.x * 128, bn = blockIdx.y * 128;
  int fr = lane & 15, kq = lane >> 4;
  f32x4 acc[4][4] = {};

  int sr = t >> 2, sc = (t & 3) * 8;
  const u16* Ar0 = A + (size_t)(bm + sr) * K + sc;
  const u16* Ar1 = A + (size_t)(bm + sr + 64) * K + sc;
  const u16* Br0 = Bt + (size_t)(bn + sr) * K + sc;
  const u16* Br1 = Bt + (size_t)(bn + sr + 64) * K + sc;
  u16* lA0 = &lsA[sr][sc];
  u16* lA1 = &lsA[sr + 64][sc];
  u16* lB0 = &lsB[sr][sc];
  u16* lB1 = &lsB[sr + 64][sc];

  for (int k0 = 0; k0 < K; k0 += 32) {
    gload_lds16(Ar0 + k0, lA0);
    gload_lds16(Ar1 + k0, lA1);
    gload_lds16(Br0 + k0, lB0);
    gload_lds16(Br1 + k0, lB1);
    __syncthreads();  // drains vmcnt(0): LDS tiles complete
    bf16x8 af[4], bfr[4];
#pragma unroll
    for (int i = 0; i < 4; ++i) af[i] = as_bf16x8(*(const u16x8*)&lsA[wm + i * 16 + fr][kq * 8]);
#pragma unroll
    for (int j = 0; j < 4; ++j) bfr[j] = as_bf16x8(*(const u16x8*)&lsB[wn + j * 16 + fr][kq * 8]);
#pragma unroll
    for (int i = 0; i < 4; ++i)
#pragma unroll
      for (int j = 0; j < 4; ++j)
        acc[i][j] = __builtin_amdgcn_mfma_f32_16x16x32_bf16(af[i], bfr[j], acc[i][j], 0, 0, 0);
    __syncthreads();  // protect LDS from next-iter staging
  }
#pragma unroll
  for (int i = 0; i < 4; ++i)
#pragma unroll
    for (int j = 0; j < 4; ++j)
#pragma unroll
      for (int r = 0; r < 4; ++r) {
        int row = bm + wm + i * 16 + kq * 4 + r;
        int col = bn + wn + j * 16 + fr;
        if (C_F32) ((float*)Cp)[(size_t)row * N + col] = acc[i][j][r];
        else       ((u16*)Cp)[(size_t)row * N + col] = f2bf(acc[i][j][r]);
      }
}

// ---------------------------------------------------------------------------
// RoPE in-place on bf16 Q [BS][H_] and K [BS][KVD].
// ---------------------------------------------------------------------------
__global__ __launch_bounds__(256) void rope_kernel(u16* __restrict__ Q,
                                                   u16* __restrict__ Kp) {
  int idx = blockIdx.x * 256 + threadIdx.x;  // BS * 40 * 64 total
  int j = idx & 63;
  int rem = idx >> 6;
  int hh = rem % 40;
  int tok = rem / 40;
  float p = (float)(tok % S_);
  float freq = __expf((float)j * (-9.210340371976184f / 64.0f));  // 10000^(-j/64)
  float sn, cs;
  __sincosf(p * freq, &sn, &cs);
  u16* base = (hh < NH) ? (Q + (size_t)tok * H_ + (size_t)hh * HD)
                        : (Kp + (size_t)tok * KVD + (size_t)(hh - NH) * HD);
  float x1 = bf2f(base[j]), x2 = bf2f(base[j + 64]);
  base[j]      = f2bf(x1 * cs - x2 * sn);
  base[j + 64] = f2bf(x2 * cs + x1 * sn);
}

// ---------------------------------------------------------------------------
// Flash attention, causal, GQA(4).
// grid: (S_/32, NKV, B_), 8 waves/block.
// Block covers 32 q-rows x 4 heads: wave w handles head kvh*4+(w&3),
// q-subtile u=(w>>2) (rows q0+u*16 .. +15).  K/V tiles staged once per
// iteration in LDS and shared by all 8 waves (8x traffic cut per q-row).
// T14 async-STAGE: tile kt+1 loaded to regs right after staging barrier,
// written to LDS at top of next iteration (global latency hidden by compute).
// qt reversed so longest (diagonal-heavy) blocks dispatch first.
// ---------------------------------------------------------------------------
__global__ __launch_bounds__(512) void flash_attn(const u16* __restrict__ Q,
                                                  const u16* __restrict__ Kp,
                                                  const u16* __restrict__ Vt,
                                                  u16* __restrict__ O) {
  __shared__ __align__(16) u16 Ks[64 * 128];   // [kv 64][d 128], swizzled
  __shared__ __align__(16) u16 Vs[128 * 64];   // [d 128][kv 64], swizzled
  __shared__ u16 Plds[8][16][72];              // per-wave P tile, +8 pad
  int qt = (gridDim.x - 1) - blockIdx.x;       // longest blocks first
  int kvh = blockIdx.y, b = blockIdx.z;
  int t = threadIdx.x, lane = t & 63, w = t >> 6;
  int h = kvh * 4 + (w & 3);                   // this wave's head
  int u = w >> 2;                              // q-subtile within block
  int fr = lane & 15, kq = lane >> 4;
  int q0 = qt * 32 + u * 16;                   // this wave's 16 q-rows

  const u16* qbase = Q + (size_t)(b * S_ + q0 + fr) * H_ + (size_t)h * HD;
  bf16x8 qf[4];
#pragma unroll
  for (int kk = 0; kk < 4; ++kk) qf[kk] = as_bf16x8(*(const u16x8*)(qbase + kk * 32 + kq * 8));

  f32x4 o[8] = {};
  float mrow[4] = {-1e30f, -1e30f, -1e30f, -1e30f};
  float lrow[4] = {0.f, 0.f, 0.f, 0.f};

  const u16* kbase = Kp + (size_t)(b * S_) * KVD + (size_t)kvh * HD;
  const u16* vbase = Vt + (size_t)(b * NKV + kvh) * ((size_t)HD * S_);
  const float scale = 0.08838834764831845f;  // 1/sqrt(128)

  // staging geometry (512 threads): K 64x256B in 16B chunks (2/thread),
  // V 128x128B in 16B loads split to two swizzled 8B writes (2/thread).
  int krow0 = t >> 4, kc = t & 15;             // K: idx = ps*512 + t
  int vrow0 = t >> 3, vc = t & 7;              // V: idx = ps*512 + t

  int niter = (qt * 32 + 31) / 64 + 1;

  // ---- prologue: load tile 0 into regs
  u16x8 kreg[2], vreg[2];
#pragma unroll
  for (int ps = 0; ps < 2; ++ps) {
    int row = krow0 + ps * 32;
    kreg[ps] = *(const u16x8*)(kbase + (size_t)row * KVD + kc * 8);
    int vrow = vrow0 + ps * 64;
    vreg[ps] = *(const u16x8*)(vbase + (size_t)vrow * S_ + vc * 8);
  }

  for (int kt = 0; kt < niter; ++kt) {
    int k0 = kt * 64;
    if (kt) __syncthreads();   // all waves done reading LDS tile kt-1
    // ---- write staged regs -> LDS (K: 16B chunks, chunk' = c ^ (row&15))
#pragma unroll
    for (int ps = 0; ps < 2; ++ps) {
      int row = krow0 + ps * 32;
      *(u16x8*)&Ks[row * 128 + ((kc ^ row) & 15) * 8] = kreg[ps];
      int vrow = vrow0 + ps * 64;
      u16x4 lo, hi;
#pragma unroll
      for (int i = 0; i < 4; ++i) { lo[i] = vreg[ps][i]; hi[i] = vreg[ps][4 + i]; }
      *(u16x4*)&Vs[vrow * 64 + (((2 * vc) ^ (vrow & 15)) * 4)] = lo;
      *(u16x4*)&Vs[vrow * 64 + (((2 * vc + 1) ^ (vrow & 15)) * 4)] = hi;
    }
    __syncthreads();           // tile kt visible to all waves
    // ---- T14: issue loads for tile kt+1 (consumed next iteration)
    if (kt + 1 < niter) {
      int k1 = k0 + 64;
#pragma unroll
      for (int ps = 0; ps < 2; ++ps) {
        int row = krow0 + ps * 32;
        kreg[ps] = *(const u16x8*)(kbase + (size_t)(k1 + row) * KVD + kc * 8);
        int vrow = vrow0 + ps * 64;
        vreg[ps] = *(const u16x8*)(vbase + (size_t)vrow * S_ + k1 + vc * 8);
      }
    }

    // ---- S = Q K^T from LDS
    f32x4 s[4] = {};
#pragma unroll
    for (int kk = 0; kk < 4; ++kk) {
#pragma unroll
      for (int j = 0; j < 4; ++j) {
        bf16x8 kf = as_bf16x8(*(const u16x8*)&Ks[(j * 16 + fr) * 128 + (((kk * 4 + kq) ^ fr) & 15) * 8]);
        s[j] = __builtin_amdgcn_mfma_f32_16x16x32_bf16(qf[kk], kf, s[j], 0, 0, 0);
      }
    }
    // ---- scale + causal mask + row max
    float mt[4] = {-1e30f, -1e30f, -1e30f, -1e30f};
#pragma unroll
    for (int j = 0; j < 4; ++j) {
      int kv = k0 + j * 16 + fr;
#pragma unroll
      for (int r = 0; r < 4; ++r) {
        int qr = q0 + kq * 4 + r;
        float sv = (kv <= qr) ? s[j][r] * scale : -1e30f;
        s[j][r] = sv;
        mt[r] = fmaxf(mt[r], sv);
      }
    }
#pragma unroll
    for (int off = 1; off < 16; off <<= 1)
#pragma unroll
      for (int r = 0; r < 4; ++r) mt[r] = fmaxf(mt[r], __shfl_xor(mt[r], off, 64));

    float alpha[4], lt[4];
#pragma unroll
    for (int r = 0; r < 4; ++r) {
      float mn = fmaxf(mrow[r], mt[r]);
      alpha[r] = __expf(mrow[r] - mn);
      mrow[r] = mn;
      lt[r] = 0.f;
    }
#pragma unroll
    for (int j = 0; j < 4; ++j)
#pragma unroll
      for (int r = 0; r < 4; ++r) {
        float p = __expf(s[j][r] - mrow[r]);
        s[j][r] = p;
        lt[r] += p;
      }
#pragma unroll
    for (int off = 1; off < 16; off <<= 1)
#pragma unroll
      for (int r = 0; r < 4; ++r) lt[r] += __shfl_xor(lt[r], off, 64);
#pragma unroll
    for (int r = 0; r < 4; ++r) lrow[r] = lrow[r] * alpha[r] + lt[r];
#pragma unroll
    for (int tt = 0; tt < 8; ++tt)
#pragma unroll
      for (int r = 0; r < 4; ++r) o[tt][r] *= alpha[r];

    // ---- P (C-layout) -> per-wave LDS -> A-layout frags
#pragma unroll
    for (int j = 0; j < 4; ++j)
#pragma unroll
      for (int r = 0; r < 4; ++r)
        Plds[w][kq * 4 + r][j * 16 + fr] = f2bf(s[j][r]);

#pragma unroll
    for (int st = 0; st < 2; ++st) {
      bf16x8 pf = as_bf16x8(*(const u16x8*)&Plds[w][fr][st * 32 + kq * 8]);
#pragma unroll
      for (int tt = 0; tt < 8; ++tt) {
        int rr = tt * 16 + fr;
        int s0 = ((st * 8 + kq * 2) ^ (fr & 15)) * 4;
        int s1 = ((st * 8 + kq * 2 + 1) ^ (fr & 15)) * 4;
        u16x4 lo = *(const u16x4*)&Vs[rr * 64 + s0];
        u16x4 hi = *(const u16x4*)&Vs[rr * 64 + s1];
        u16x8 vv;
#pragma unroll
        for (int i = 0; i < 4; ++i) { vv[i] = lo[i]; vv[4 + i] = hi[i]; }
        o[tt] = __builtin_amdgcn_mfma_f32_16x16x32_bf16(pf, as_bf16x8(vv), o[tt], 0, 0, 0);
      }
    }
  }

  float inv[4];
#pragma unroll
  for (int r = 0; r < 4; ++r) inv[r] = 1.0f / lrow[r];
  u16* obase = O + (size_t)(b * S_ + q0) * H_ + (size_t)h * HD;
#pragma unroll
  for (int tt = 0; tt < 8; ++tt)
#pragma unroll
    for (int r = 0; r < 4; ++r)
      obase[(size_t)(kq * 4 + r) * H_ + tt * 16 + fr] = f2bf(o[tt][r] * inv[r]);
}

// ---------------------------------------------------------------------------
extern "C" void kernel_launch(void* const* d_in, const int* in_sizes, int n_in,
                              void* d_out, int out_size, void* d_ws, size_t ws_size,
                              hipStream_t stream) {
  const float* X  = (const float*)d_in[0];
  const float* Wq = (const float*)d_in[2];
  const float* Wk = (const float*)d_in[3];
  const float* Wv = (const float*)d_in[4];
  const float* Wo = (const float*)d_in[5];
  float* out = (float*)d_out;

  // ws (80 MiB): K 8 | Vt 8 | {Xb -> Ob} 32 | Wt 32   (bf16)
  char* ws = (char*)d_ws;
  u16* Kb = (u16*)ws;
  u16* Vt = (u16*)(ws + 8ull  * 1024 * 1024);
  u16* Xb = (u16*)(ws + 16ull * 1024 * 1024);
  u16* Ob = (u16*)(ws + 16ull * 1024 * 1024);
  u16* Wt = (u16*)(ws + 48ull * 1024 * 1024);
  // d_out is 64 MiB fp32; park bf16 Q (32 MiB) and pre-transpose V (8 MiB)
  // there — both dead before the final GEMM overwrites all of d_out.
  u16* Qb = (u16*)d_out;
  u16* Vb = (u16*)((char*)d_out + 32ull * 1024 * 1024);

  dim3 blk(256);
  dim3 blk8(512);

  // X -> bf16 (once; enables global_load_lds staging in all GEMMs)
  conv_bf16<<<dim3((size_t)BS * H_ / 8 / 256), blk, 0, stream>>>(X, Xb);

  // Q = X @ Wq
  conv_transpose_w<<<dim3(64, 64), blk, 0, stream>>>(Wq, Wt, H_, H_);
  gemm_bt_lds<false><<<dim3(32, 32), blk, 0, stream>>>(Xb, Wt, Qb, BS, H_, H_);
  // K = X @ Wk
  conv_transpose_w<<<dim3(64, 16), blk, 0, stream>>>(Wk, Wt, KVD, H_);
  gemm_bt_lds<false><<<dim3(32, 8), blk, 0, stream>>>(Xb, Wt, Kb, BS, KVD, H_);
  // V = X @ Wv
  conv_transpose_w<<<dim3(64, 16), blk, 0, stream>>>(Wv, Wt, KVD, H_);
  gemm_bt_lds<false><<<dim3(32, 8), blk, 0, stream>>>(Xb, Wt, Vb, BS, KVD, H_);
  // RoPE in-place on Q and K
  rope_kernel<<<dim3((BS * 40 * 64) / 256), blk, 0, stream>>>(Qb, Kb);
  // V -> Vt
  transpose_v<<<dim3(S_ / 64, HD / 64, B_ * NKV), blk, 0, stream>>>(Vb, Vt);
  // attention -> Ob
  flash_attn<<<dim3(S_ / 32, NKV, B_), blk8, 0, stream>>>(Qb, Kb, Vt, Ob);
  // out = Ob @ Wo  (fp32 out, overwrites all of d_out)
  conv_transpose_w<<<dim3(64, 64), blk, 0, stream>>>(Wo, Wt, H_, H_);
  gemm_bt_lds<true><<<dim3(32, 32), blk, 0, stream>>>(Ob, Wt, out, BS, H_, H_);
}